// Round 2
// baseline (367.110 us; speedup 1.0000x reference)
//
#include <hip/hip_runtime.h>
#include <hip/hip_fp16.h>

#define B_  8
#define D_  512
#define H_  512
#define L_  8192
#define O2_ 1024   // 2*H

typedef __attribute__((ext_vector_type(8))) short   bf16x8;
typedef __attribute__((ext_vector_type(4))) float   floatx4;
typedef __attribute__((ext_vector_type(8))) unsigned short ushort8_t;
typedef __attribute__((ext_vector_type(4))) unsigned short ushort4_t;

__device__ __forceinline__ unsigned short f2bf(float f) {
    union { float f; unsigned u; } x; x.f = f;
    unsigned u = x.u;
    u += 0x7FFFu + ((u >> 16) & 1u);   // round-to-nearest-even
    return (unsigned short)(u >> 16);
}

// async global->LDS, 16B per lane; LDS dest = wave-uniform base + lane*16
__device__ __forceinline__ void async_load16(const void* g, void* l) {
    __builtin_amdgcn_global_load_lds(
        (const __attribute__((address_space(1))) unsigned int*)g,
        (__attribute__((address_space(3))) unsigned int*)l,
        16, 0, 0);
}

#define WAITVM(N) asm volatile("s_waitcnt vmcnt(" #N ")" ::: "memory")

// ---------------- K0: reorder W rows (pair-interleave) + convert to bf16 ----
__global__ __launch_bounds__(256) void prep_w(const float* __restrict__ W,
                                              unsigned short* __restrict__ Wr) {
    int idx  = blockIdx.x * 256 + threadIdx.x;
    int flat = idx * 4;
    int o = flat >> 9;        // /512
    int d = flat & 511;
    int src_o = (o & 1) ? (H_ + (o >> 1)) : (o >> 1);
    float4 wv = *(const float4*)(W + (size_t)src_o * D_ + d);
    ushort4_t r;
    r.x = f2bf(wv.x); r.y = f2bf(wv.y); r.z = f2bf(wv.z); r.w = f2bf(wv.w);
    *(ushort4_t*)(Wr + (size_t)o * D_ + d) = r;
}

// ---------------- K1: x [B][D][L] fp32  ->  xT [B][L][D] bf16 ---------------
__global__ __launch_bounds__(256) void transpose_x(const float* __restrict__ x,
                                                   unsigned short* __restrict__ xT) {
    __shared__ float T[64][65];
    const int b  = blockIdx.z;
    const int d0 = blockIdx.y * 64;
    const int l0 = blockIdx.x * 64;
    const int tid = threadIdx.x;

    const int c  = tid & 15;       // float4 column within l
    const int r0 = tid >> 4;       // starting d-row
    const float* xp = x + ((size_t)b * D_ + d0) * L_ + l0;
    for (int rr = r0; rr < 64; rr += 16) {
        float4 vv = *(const float4*)(xp + (size_t)rr * L_ + c * 4);
        T[c * 4 + 0][rr] = vv.x;
        T[c * 4 + 1][rr] = vv.y;
        T[c * 4 + 2][rr] = vv.z;
        T[c * 4 + 3][rr] = vv.w;
    }
    __syncthreads();

    const int dc  = (tid & 7) * 8;  // d chunk (8 bf16 = 16B store)
    const int lr0 = tid >> 3;       // l row
    unsigned short* op = xT + ((size_t)b * L_ + l0) * D_ + d0;
    for (int lr = lr0; lr < 64; lr += 32) {
        ushort8_t o8;
        o8[0] = f2bf(T[lr][dc + 0]); o8[1] = f2bf(T[lr][dc + 1]);
        o8[2] = f2bf(T[lr][dc + 2]); o8[3] = f2bf(T[lr][dc + 3]);
        o8[4] = f2bf(T[lr][dc + 4]); o8[5] = f2bf(T[lr][dc + 5]);
        o8[6] = f2bf(T[lr][dc + 6]); o8[7] = f2bf(T[lr][dc + 7]);
        *(ushort8_t*)(op + (size_t)lr * D_ + dc) = o8;
    }
}

// ---------------- K2: hg = Wr @ xT^T — 256x256 tile, 8 waves, BK=32, -------
// 4 LDS buffers, 3-tile prefetch depth, counted vmcnt (never 0 in loop),
// setprio around MFMA clusters. XOR swizzle (both sides): DMA dest linear,
// source chunk = (i&3)^((i>>3)&3); read chunk = quad^((lm>>1)&3).
// Conflict-free: per 16-lane b128 phase, 8 bank-columns hit exactly 2x.
__global__ __launch_bounds__(512, 2) void gemm_hg256(const unsigned short* __restrict__ Wr,
                                                     const unsigned short* __restrict__ xT,
                                                     __half* __restrict__ hg) {
    __shared__ __align__(16) unsigned short As[4 * 256 * 32];   // 64 KB
    __shared__ __align__(16) unsigned short Bs[4 * 256 * 32];   // 64 KB

    const int b  = blockIdx.z;
    const int o0 = blockIdx.y * 256;
    const int l0 = blockIdx.x * 256;
    const int tid  = threadIdx.x;
    const int lane = tid & 63;
    const int w    = tid >> 6;          // 0..7 ; wave grid 2(M) x 4(N)
    const int wm   = (w >> 2) * 128;    // M (o) offset of wave
    const int wn   = (w & 3) * 64;      // N (l) offset of wave
    const int lm   = lane & 15;
    const int quad = lane >> 4;

    // fragment LDS element offsets (swizzled chunk; (r>>1)&3 == (lm>>1)&3
    // because all row bases are multiples of 16)
    const int pq = (quad ^ ((lm >> 1) & 3)) * 8;
    int offA[8], offB[4];
    #pragma unroll
    for (int mi = 0; mi < 8; ++mi) offA[mi] = (wm + mi * 16 + lm) * 32 + pq;
    #pragma unroll
    for (int ni = 0; ni < 4; ++ni) offB[ni] = (wn + ni * 16 + lm) * 32 + pq;

    // staging: wave w covers rows [p*128 + w*16, +16); lane i -> row +(i>>2),
    // physical chunk i&3 sources logical chunk (i&3)^((i>>3)&3)
    const int sr  = lane >> 2;
    const int scg = (lane & 3) ^ ((lane >> 3) & 3);
    const unsigned short* Ag0 = Wr + (size_t)(o0 + w * 16 + sr) * D_ + scg * 8;
    const unsigned short* Bg0 = xT + ((size_t)b * L_ + l0 + w * 16 + sr) * D_ + scg * 8;
    const int ldsP0 = w * 512;          // element offset of rows [w*16, +16)
    const int ldsP1 = 4096 + w * 512;   // rows [128 + w*16, +16)

    floatx4 acc[8][4];
    #pragma unroll
    for (int mi = 0; mi < 8; ++mi)
        #pragma unroll
        for (int ni = 0; ni < 4; ++ni)
            acc[mi][ni] = (floatx4){0.f, 0.f, 0.f, 0.f};

    // prologue: stage tiles 0..2 (12 loads/wave, 4 per tile in order A0 A1 B0 B1)
    #pragma unroll
    for (int t = 0; t < 3; ++t) {
        async_load16(Ag0 + (size_t)t * 32,                    &As[t * 8192 + ldsP0]);
        async_load16(Ag0 + (size_t)t * 32 + 128 * (size_t)D_, &As[t * 8192 + ldsP1]);
        async_load16(Bg0 + (size_t)t * 32,                    &Bs[t * 8192 + ldsP0]);
        async_load16(Bg0 + (size_t)t * 32 + 128 * (size_t)D_, &Bs[t * 8192 + ldsP1]);
    }
    WAITVM(8);                       // tile 0 staged; tiles 1,2 in flight
    __builtin_amdgcn_s_barrier();

// one K-tile (BK=32): 2 phases of {ds_read | stage-issue | barrier | 16 MFMA}.
// End-of-tile VMW ensures tile T+1 is staged before the next flip barrier.
#define GEMM_TILE(BUF, T, DO_STAGE, VMW)                                          \
  {                                                                               \
    bf16x8 af[4], bfv[4];                                                         \
    const int base_ = (BUF) * 8192;                                               \
    _Pragma("unroll")                                                             \
    for (int mi_ = 0; mi_ < 4; ++mi_)                                             \
        af[mi_] = *(const bf16x8*)&As[base_ + offA[mi_]];                         \
    _Pragma("unroll")                                                             \
    for (int ni_ = 0; ni_ < 4; ++ni_)                                             \
        bfv[ni_] = *(const bf16x8*)&Bs[base_ + offB[ni_]];                        \
    if (DO_STAGE) {                                                               \
        const int nb_ = ((T) + 3) & 3;                                            \
        async_load16(Ag0 + (size_t)((T) + 3) * 32,                    &As[nb_ * 8192 + ldsP0]); \
        async_load16(Ag0 + (size_t)((T) + 3) * 32 + 128 * (size_t)D_, &As[nb_ * 8192 + ldsP1]); \
    }                                                                             \
    __builtin_amdgcn_s_barrier();                                                 \
    __builtin_amdgcn_s_setprio(1);                                                \
    _Pragma("unroll")                                                             \
    for (int mi_ = 0; mi_ < 4; ++mi_)                                             \
        _Pragma("unroll")                                                         \
        for (int ni_ = 0; ni_ < 4; ++ni_)                                         \
            acc[mi_][ni_] = __builtin_amdgcn_mfma_f32_16x16x32_bf16(              \
                af[mi_], bfv[ni_], acc[mi_][ni_], 0, 0, 0);                       \
    __builtin_amdgcn_s_setprio(0);                                                \
    __builtin_amdgcn_s_barrier();                                                 \
    _Pragma("unroll")                                                             \
    for (int mi_ = 0; mi_ < 4; ++mi_)                                             \
        af[mi_] = *(const bf16x8*)&As[base_ + offA[4 + mi_]];                     \
    if (DO_STAGE) {                                                               \
        const int nb_ = ((T) + 3) & 3;                                            \
        async_load16(Bg0 + (size_t)((T) + 3) * 32,                    &Bs[nb_ * 8192 + ldsP0]); \
        async_load16(Bg0 + (size_t)((T) + 3) * 32 + 128 * (size_t)D_, &Bs[nb_ * 8192 + ldsP1]); \
    }                                                                             \
    __builtin_amdgcn_s_barrier();                                                 \
    __builtin_amdgcn_s_setprio(1);                                                \
    _Pragma("unroll")                                                             \
    for (int mi_ = 0; mi_ < 4; ++mi_)                                             \
        _Pragma("unroll")                                                         \
        for (int ni_ = 0; ni_ < 4; ++ni_)                                         \
            acc[4 + mi_][ni_] = __builtin_amdgcn_mfma_f32_16x16x32_bf16(          \
                af[mi_], bfv[ni_], acc[4 + mi_][ni_], 0, 0, 0);                   \
    __builtin_amdgcn_s_setprio(0);                                                \
    VMW;                                                                          \
    __builtin_amdgcn_s_barrier();                                                 \
  }

    // steady state: during tile t issue tile t+3 (buffer (t-1)&3, retired at
    // end of tile t-1). In flight at tile end: t+1(4), t+2(4), t+3(4) -> vmcnt(8)
    // waits exactly for tile t+1. Tail peels 8 -> 4 -> 0.
    #pragma unroll 1
    for (int t = 0; t < 13; ++t) {
        GEMM_TILE(t & 3, t, true, WAITVM(8));
    }
    GEMM_TILE(1, 13, false, WAITVM(4));
    GEMM_TILE(2, 14, false, WAITVM(0));
    GEMM_TILE(3, 15, false, (void)0);

#undef GEMM_TILE

    // epilogue: D[row = quad*4 + r][col = lm] per 16x16 tile
    __half* hp = hg + ((size_t)b * O2_ + o0 + wm + quad * 4) * L_ + l0 + wn + lm;
    #pragma unroll
    for (int mi = 0; mi < 8; ++mi)
        #pragma unroll
        for (int ni = 0; ni < 4; ++ni)
            #pragma unroll
            for (int r = 0; r < 4; ++r)
                hp[(size_t)(mi * 16 + r) * L_ + ni * 16] = __float2half(acc[mi][ni][r]);
}

// ---------------- K3: per-(b,k) chunked scan — shfl wave scan, 3 barriers ---
__global__ __launch_bounds__(256) void scan_seq(const __half* __restrict__ hg,
                                                const float* __restrict__ bias,
                                                float* __restrict__ out) {
    __shared__ __align__(16) unsigned int sBuf[256 * 40];
    __shared__ float wA[4];
    __shared__ float wB[4];
    unsigned int* sH = sBuf;
    unsigned int* sG = sBuf + 256 * 20;

    const int bid = blockIdx.x;
    const int b = bid >> 9;
    const int k = bid & 511;
    const int t = threadIdx.x;
    const int lane = t & 63;
    const int wid  = t >> 6;

    const uint4* hq = (const uint4*)(hg + ((size_t)b * O2_ + 2 * k) * L_);
    const uint4* gq = hq + (L_ / 8);   // next row (gate)

    #pragma unroll
    for (int j = 0; j < 4; ++j) {
        int idx = t + 256 * j;               // uint4 index 0..1023
        uint4 hv = hq[idx];
        uint4 gv = gq[idx];
        int cc = idx >> 2, ss = idx & 3;     // chunk 16 uints, pad to 20
        *(uint4*)&sH[cc * 20 + ss * 4] = hv;
        *(uint4*)&sG[cc * 20 + ss * 4] = gv;
    }
    const float bh = bias[k];
    const float bg = bias[H_ + k];
    __syncthreads();                                           // barrier 1

    float c[32], v[32];
    float A = 1.f, Bv = 0.f;
    #pragma unroll
    for (int j4 = 0; j4 < 4; ++j4) {
        uint4 hv = *(const uint4*)&sH[t * 20 + j4 * 4];
        uint4 gv = *(const uint4*)&sG[t * 20 + j4 * 4];
        unsigned hu[4] = {hv.x, hv.y, hv.z, hv.w};
        unsigned gu[4] = {gv.x, gv.y, gv.z, gv.w};
        #pragma unroll
        for (int q = 0; q < 4; ++q) {
            __half2 h2 = *(const __half2*)&hu[q];
            __half2 g2 = *(const __half2*)&gu[q];
            #pragma unroll
            for (int e = 0; e < 2; ++e) {
                const int i = j4 * 8 + q * 2 + e;
                float hf = (e ? __high2float(h2) : __low2float(h2)) + bh;
                float gf = (e ? __high2float(g2) : __low2float(g2)) + bg;
                float ex  = __expf(gf);
                float inv = 1.f / (1.f + ex);
                float ci  = inv;        // sigmoid(-gate)
                float zi  = ex * inv;   // sigmoid(gate)
                float gv2 = (hf >= 0.f) ? (1.f + hf) : __expf(hf);
                float vi  = zi * gv2;
                c[i] = ci; v[i] = vi;
                Bv = ci * Bv + vi;
                A *= ci;
            }
        }
    }

    // wave-level inclusive scan of (A,B) composition, no barriers
    #pragma unroll
    for (int off = 1; off < 64; off <<= 1) {
        float pA = __shfl_up(A, off);
        float pB = __shfl_up(Bv, off);
        if (lane >= off) { Bv = Bv + A * pB; A = A * pA; }
    }

    if (lane == 63) { wA[wid] = A; wB[wid] = Bv; }
    __syncthreads();                                           // barrier 2

    // carry from preceding waves (composed in order)
    float cB = 0.f;
    for (int p = 0; p < wid; ++p) cB = wB[p] + wA[p] * cB;

    // exclusive lane prefix within wave
    float eA = __shfl_up(A, 1);
    float eB = __shfl_up(Bv, 1);
    if (lane == 0) { eA = 1.f; eB = 0.f; }
    float hr = eB + eA * cB;   // H entering this thread's chunk (H0 = 0)

    // outputs into LDS (chunk stride 36 floats), then coalesced store.
    float* sO = (float*)sBuf;
    #pragma unroll
    for (int i = 0; i < 32; i += 4) {
        float4 o4;
        o4.x = hr = c[i + 0] * hr + v[i + 0];
        o4.y = hr = c[i + 1] * hr + v[i + 1];
        o4.z = hr = c[i + 2] * hr + v[i + 2];
        o4.w = hr = c[i + 3] * hr + v[i + 3];
        *(float4*)&sO[t * 36 + i] = o4;
    }
    __syncthreads();                                           // barrier 3

    float4* op4 = (float4*)(out + ((size_t)b * H_ + k) * L_);
    #pragma unroll
    for (int j = 0; j < 8; ++j) {
        int idx = t + 256 * j;               // float4 index 0..2047
        int cc = idx >> 3, ss = idx & 7;     // chunk 32 floats, pad to 36
        op4[idx] = *(const float4*)&sO[cc * 36 + ss * 4];
    }
}

// ---------------- fallback: fully fused naive (if ws too small) -------------
__global__ __launch_bounds__(256) void fused_naive(const float* __restrict__ x,
                                                   const float* __restrict__ W,
                                                   const float* __restrict__ bias,
                                                   float* __restrict__ out) {
    __shared__ float Wh[512];
    __shared__ float Wg[512];
    __shared__ float sA[256];
    __shared__ float sB[256];
    const int bid = blockIdx.x;
    const int b = bid >> 9;
    const int k = bid & 511;
    const int t = threadIdx.x;

    for (int i = t; i < 512; i += 256) {
        Wh[i] = W[(size_t)k * D_ + i];
        Wg[i] = W[(size_t)(H_ + k) * D_ + i];
    }
    const float bh = bias[k];
    const float bg = bias[H_ + k];
    __syncthreads();

    float Hc = 0.f;
    const float* xb = x + (size_t)b * D_ * L_;
    for (int ch = 0; ch < 32; ++ch) {
        const int l = ch * 256 + t;
        float ah = bh, ag = bg;
        for (int d = 0; d < 512; ++d) {
            float xv = xb[(size_t)d * L_ + l];
            ah += Wh[d] * xv;
            ag += Wg[d] * xv;
        }
        float e   = __expf(ag);
        float inv = 1.f / (1.f + e);
        float ci  = inv;
        float zi  = e * inv;
        float gv  = (ah >= 0.f) ? (1.f + ah) : __expf(ah);
        float vi  = zi * gv;

        float A = ci, Bv = vi;
        sA[t] = A; sB[t] = Bv;
        __syncthreads();
        for (int off = 1; off < 256; off <<= 1) {
            float pA = 1.f, pB = 0.f;
            if (t >= off) { pA = sA[t - off]; pB = sB[t - off]; }
            __syncthreads();
            Bv = Bv + A * pB;
            A  = A * pA;
            sA[t] = A; sB[t] = Bv;
            __syncthreads();
        }
        out[((size_t)b * H_ + k) * L_ + l] = A * Hc + Bv;
        float An = sA[255], Bn = sB[255];
        Hc = An * Hc + Bn;
        __syncthreads();
    }
}

extern "C" void kernel_launch(void* const* d_in, const int* in_sizes, int n_in,
                              void* d_out, int out_size, void* d_ws, size_t ws_size,
                              hipStream_t stream) {
    const float* x    = (const float*)d_in[0];
    const float* W    = (const float*)d_in[1];
    const float* bias = (const float*)d_in[2];
    float* out = (float*)d_out;

    const size_t xT_bytes = (size_t)B_ * L_ * D_ * 2;        //  67,108,864
    const size_t Wr_bytes = (size_t)O2_ * D_ * 2;            //   1,048,576
    const size_t hg_bytes = (size_t)B_ * O2_ * L_ * 2;       // 134,217,728
    const size_t need = xT_bytes + Wr_bytes + hg_bytes;      // ~202 MB

    if (ws_size >= need) {
        char* ws = (char*)d_ws;
        unsigned short* xT = (unsigned short*)ws;
        unsigned short* Wr = (unsigned short*)(ws + xT_bytes);
        __half*         hg = (__half*)(ws + xT_bytes + Wr_bytes);

        prep_w<<<512, 256, 0, stream>>>(W, Wr);
        transpose_x<<<dim3(L_ / 64, D_ / 64, B_), 256, 0, stream>>>(x, xT);
        gemm_hg256<<<dim3(L_ / 256, O2_ / 256, B_), 512, 0, stream>>>(Wr, xT, hg);
        scan_seq<<<B_ * H_, 256, 0, stream>>>(hg, bias, out);
    } else {
        fused_naive<<<B_ * H_, 256, 0, stream>>>(x, W, bias, out);
    }
}